// Round 7
// baseline (991.804 us; speedup 1.0000x reference)
//
#include <hip/hip_runtime.h>
#include <hip/hip_fp16.h>

// GCN 2-layer forward on gfx950 — bucket-major PUSH aggregation consuming the
// raw binned edge list directly (no sorted CSR, no esrc, no k_bsort, no pad
// machinery), fp16 intermediates (fp32 accumulation), MFMA layer-1 transform,
// W2 projection fused into the layer-1 push epilogue (h never materializes).
// R16 = R15 resubmitted verbatim (R6 bench was an infra failure: container
// acquisition died twice; source audit found no hang/fault path — all
// syncthreads uniform, all writes bounds-guarded, workspace non-overlapping).
// R15: lessons — R5 proved scatter/aggregation must be BUCKET-major (edge-major
// random 4B writes cost 113MB of HBM write-allocate); R3/R4 proved the gathers
// are y-row-read-bound (pads and MLP are free). So: k_bin (bucket-clustered
// ebuf, fused global degree atomics) feeds LDS-accumulator push kernels.
// dinv is computed inline as rsqrtf(deg+1) everywhere (same instruction ->
// identical values; no dinv array, no scan kernel).
// F=128, H=64, O=10. N=100k, E=1.6M.
static constexpr int F = 128;
static constexpr int H = 64;
static constexpr int O = 10;
static constexpr int PSU = 6;       // zs row stride in uints (12 halves, [5]=0 pad)
static constexpr int BKSH = 7;      // bucket = dst >> 7 (128 nodes/bucket)
static constexpr int CAP = 2560;    // per-bucket edge capacity (mean 2046, +11σ)
static constexpr int EPB = 4096;    // edges per block in k_bin
static constexpr int XPAD = 136;    // xh LDS row stride in halves (128 + 8)

typedef _Float16 half8 __attribute__((ext_vector_type(8)));
typedef float floatx4 __attribute__((ext_vector_type(4)));

// blocks [0,nbz): zero deg; block nbz: zero bcntg[1024];
// blocks nbz+1 ..: build W1f = fp16 W1 in MFMA B-fragment order.
__global__ __launch_bounds__(256) void k_init(int* __restrict__ deg,
                                              int* __restrict__ bcntg,
                                              const float* __restrict__ W1,
                                              __half* __restrict__ W1f,
                                              int n_nodes) {
    const int nbz = (n_nodes + 255) >> 8;
    int b = blockIdx.x, t = threadIdx.x;
    if (b < nbz) {
        int i = b * 256 + t;
        if (i < n_nodes) deg[i] = 0;
    } else if (b == nbz) {
#pragma unroll
        for (int u = 0; u < 4; ++u) bcntg[t + 256 * u] = 0;
    } else {
        int i = (b - nbz - 1) * 256 + t;   // 0..8191
        int j = i & 7, lane = (i >> 3) & 63, sc = i >> 9;
        int s = sc >> 2, c = sc & 3;
        int k = s * 32 + (lane >> 4) * 8 + j;
        int nn = c * 16 + (lane & 15);
        W1f[i] = __float2half(W1[k * H + nn]);
    }
}

// Bin edges by bucket = dst>>7 into bucket-contiguous packed 4B entries
// entry = (dst&127)<<17 | src (src < 2^17), two-level cursors (LDS hist +
// one global add per block per bucket). Fused: global per-node degree count.
__global__ __launch_bounds__(256) void k_bin(const int* __restrict__ src,
                                             const int* __restrict__ dst,
                                             int* __restrict__ bcntg,
                                             int* __restrict__ deg,
                                             unsigned* __restrict__ ebuf, int e_total) {
    __shared__ int hist[1024];
    __shared__ int base[1024];
    __shared__ int loc[1024];
    int t = threadIdx.x;
#pragma unroll
    for (int u = 0; u < 4; ++u) { hist[t + 256 * u] = 0; loc[t + 256 * u] = 0; }
    __syncthreads();
    int i0 = blockIdx.x * EPB;
    int i1 = min(i0 + EPB, e_total);
    int i = i0 + 4 * t;
    for (; i + 3 < i1; i += 1024) {
        int4 d4 = *(const int4*)&dst[i];
        atomicAdd(&hist[d4.x >> BKSH], 1);
        atomicAdd(&hist[d4.y >> BKSH], 1);
        atomicAdd(&hist[d4.z >> BKSH], 1);
        atomicAdd(&hist[d4.w >> BKSH], 1);
        atomicAdd(&deg[d4.x], 1);
        atomicAdd(&deg[d4.y], 1);
        atomicAdd(&deg[d4.z], 1);
        atomicAdd(&deg[d4.w], 1);
    }
    for (; i < i1; ++i) {
        int d = dst[i];
        atomicAdd(&hist[d >> BKSH], 1);
        atomicAdd(&deg[d], 1);
    }
    __syncthreads();
#pragma unroll
    for (int u = 0; u < 4; ++u) {
        int ii = t + 256 * u;
        if (hist[ii] > 0) base[ii] = atomicAdd(&bcntg[ii], hist[ii]);
    }
    __syncthreads();
    i = i0 + 4 * t;
    for (; i + 3 < i1; i += 1024) {
        int4 s4 = *(const int4*)&src[i];
        int4 d4 = *(const int4*)&dst[i];
#pragma unroll
        for (int u = 0; u < 4; ++u) {
            int s = (&s4.x)[u], d = (&d4.x)[u];
            int b = d >> BKSH;
            int r = base[b] + atomicAdd(&loc[b], 1);
            if (r < CAP)
                ebuf[(size_t)b * CAP + r] = ((unsigned)(d & 127) << 17) | (unsigned)s;
        }
    }
    for (; i < i1; ++i) {
        int s = src[i], d = dst[i];
        int b = d >> BKSH;
        int r = base[b] + atomicAdd(&loc[b], 1);
        if (r < CAP)
            ebuf[(size_t)b * CAP + r] = ((unsigned)(d & 127) << 17) | (unsigned)s;
    }
}

// y = fp16((x @ W1) * rsqrt(deg+1)) via MFMA 16x16x32 f16. 4 waves = 64 rows.
__global__ __launch_bounds__(256, 4) void k_gemm1(
    const float* __restrict__ x, const __half* __restrict__ W1f,
    const int* __restrict__ deg, __half* __restrict__ y, int n_nodes) {
    __shared__ __half xh[64 * XPAD];
    const int tid = threadIdx.x;
    const int lane = tid & 63;
    const int w = tid >> 6;
    const int row0 = blockIdx.x * 64;

    half8 bf[16];
    const uint4* wf = (const uint4*)W1f;
#pragma unroll
    for (int sc = 0; sc < 16; ++sc) {
        union { uint4 u; half8 h; } tmp;
        tmp.u = wf[sc * 64 + lane];
        bf[sc] = tmp.h;
    }

    for (int i = tid; i < 64 * 32; i += 256) {
        int r = i >> 5, k4 = i & 31;
        int gr = row0 + r;
        if (gr < n_nodes) {
            float4 v = *(const float4*)&x[(size_t)gr * F + 4 * k4];
            __half2 p0 = __floats2half2_rn(v.x, v.y);
            __half2 p1 = __floats2half2_rn(v.z, v.w);
            uint2 pk = make_uint2(*(unsigned*)&p0, *(unsigned*)&p1);
            *(uint2*)&xh[r * XPAD + 4 * k4] = pk;
        }
    }
    __syncthreads();

    const int m16 = lane & 15, quad = lane >> 4;
    floatx4 acc[4];
#pragma unroll
    for (int c = 0; c < 4; ++c) acc[c] = (floatx4){0.f, 0.f, 0.f, 0.f};
#pragma unroll
    for (int s = 0; s < 4; ++s) {
        union { uint4 u; half8 h; } ua;
        ua.u = *(const uint4*)&xh[(16 * w + m16) * XPAD + s * 32 + quad * 8];
#pragma unroll
        for (int c = 0; c < 4; ++c)
            acc[c] = __builtin_amdgcn_mfma_f32_16x16x32_f16(ua.h, bf[s * 4 + c],
                                                            acc[c], 0, 0, 0);
    }
#pragma unroll
    for (int r = 0; r < 4; ++r) {
        int grow = row0 + 16 * w + quad * 4 + r;
        if (grow < n_nodes) {
            float d = rsqrtf((float)deg[grow] + 1.0f);
#pragma unroll
            for (int c = 0; c < 4; ++c)
                y[(size_t)grow * H + c * 16 + m16] = __float2half(acc[c][r] * d);
        }
    }
}

// Push layer 1 + fused W2: one block per 128-node bucket, 512 threads.
// LDS accum [128][65] fp32 (stride 65 spreads atomic banks). Edge loop: per
// wave-iter 64 entries loaded coalesced; 8-lane groups read the 128B y row
// (uint4/lane) and ds_add_f32 into the dst row. Epilogue (g1z-verified math):
// h = relu(rsqrt(deg+1)*(acc+self) + b1); per-lane W2 partials vs w2t in LDS;
// 3-step xor fold in the 8-lane group; lane c==0 stores the packed 24B zs row.
__global__ __launch_bounds__(512) void k_push1(
    const uint4* __restrict__ yq4, const unsigned* __restrict__ ebuf,
    const int* __restrict__ bcntg, const int* __restrict__ deg,
    const float* __restrict__ b1, const float* __restrict__ W2,
    unsigned* __restrict__ zs_u, int n_nodes) {
    __shared__ float accf[128 * 65];   // 33.3 KB
    __shared__ float w2t[O * H];       // 2.56 KB, w2t[j*64+k] = W2[k*10+j]
    const int tid = threadIdx.x;
    for (int i = tid; i < 128 * 65; i += 512) accf[i] = 0.f;
    for (int i = tid; i < O * H; i += 512) w2t[i] = W2[(i & 63) * O + (i >> 6)];
    __syncthreads();
    const int b = blockIdx.x, n0 = b << BKSH;
    const int cb = min(bcntg[b], CAP);
    const unsigned* eb = ebuf + (size_t)b * CAP;
    const int l = tid & 63, c = l & 7, gb8 = l & ~7, w = tid >> 6;
    for (int kb = w * 64; kb < cb; kb += 512) {
        unsigned ent_l = (kb + l < cb) ? eb[kb + l] : 0xFFFFFFFFu;
#pragma unroll
        for (int e = 0; e < 8; ++e) {
            unsigned ent = __shfl(ent_l, gb8 + e, 64);
            if (ent == 0xFFFFFFFFu) continue;   // tail-batch only
            int dl = (int)(ent >> 17), s = (int)(ent & 0x1FFFFu);
            uint4 v = yq4[(size_t)s * 8 + c];
            float2 f0 = __half22float2(*(const __half2*)&v.x);
            float2 f1 = __half22float2(*(const __half2*)&v.y);
            float2 f2 = __half22float2(*(const __half2*)&v.z);
            float2 f3 = __half22float2(*(const __half2*)&v.w);
            float* ar = &accf[dl * 65 + 8 * c];
            atomicAdd(&ar[0], f0.x); atomicAdd(&ar[1], f0.y);
            atomicAdd(&ar[2], f1.x); atomicAdd(&ar[3], f1.y);
            atomicAdd(&ar[4], f2.x); atomicAdd(&ar[5], f2.y);
            atomicAdd(&ar[6], f3.x); atomicAdd(&ar[7], f3.y);
        }
    }
    __syncthreads();
    // epilogue: 64 nodes/pass (8 lanes/node), 2 passes over 128 nodes
    for (int n = tid >> 3; n < 128; n += 64) {
        int ng = n0 + n;
        if (ng >= n_nodes) continue;   // whole 8-lane group shares ng
        const float d = rsqrtf((float)deg[ng] + 1.0f);
        const float* ar = &accf[n * 65 + 8 * c];
        uint4 v = yq4[(size_t)ng * 8 + c];   // self-loop row
        float2 s0 = __half22float2(*(const __half2*)&v.x);
        float2 s1 = __half22float2(*(const __half2*)&v.y);
        float2 s2 = __half22float2(*(const __half2*)&v.z);
        float2 s3 = __half22float2(*(const __half2*)&v.w);
        const float4 ba = ((const float4*)b1)[2 * c];
        const float4 bb = ((const float4*)b1)[2 * c + 1];
        float h[8];
        h[0] = fmaxf(fmaf(d, ar[0] + s0.x, ba.x), 0.0f);
        h[1] = fmaxf(fmaf(d, ar[1] + s0.y, ba.y), 0.0f);
        h[2] = fmaxf(fmaf(d, ar[2] + s1.x, ba.z), 0.0f);
        h[3] = fmaxf(fmaf(d, ar[3] + s1.y, ba.w), 0.0f);
        h[4] = fmaxf(fmaf(d, ar[4] + s2.x, bb.x), 0.0f);
        h[5] = fmaxf(fmaf(d, ar[5] + s2.y, bb.y), 0.0f);
        h[6] = fmaxf(fmaf(d, ar[6] + s3.x, bb.z), 0.0f);
        h[7] = fmaxf(fmaf(d, ar[7] + s3.y, bb.w), 0.0f);
        float p[O];
#pragma unroll
        for (int j = 0; j < O; ++j) {
            float4 wa = *(const float4*)&w2t[j * 64 + 8 * c];
            float4 wb = *(const float4*)&w2t[j * 64 + 8 * c + 4];
            p[j] = h[0] * wa.x + h[1] * wa.y + h[2] * wa.z + h[3] * wa.w
                 + h[4] * wb.x + h[5] * wb.y + h[6] * wb.z + h[7] * wb.w;
        }
#pragma unroll
        for (int m = 1; m <= 4; m <<= 1) {
#pragma unroll
            for (int j = 0; j < O; ++j) p[j] += __shfl_xor(p[j], m, 64);
        }
        if (c == 0) {
            __half2 q0 = __floats2half2_rn(p[0] * d, p[1] * d);
            __half2 q1 = __floats2half2_rn(p[2] * d, p[3] * d);
            __half2 q2 = __floats2half2_rn(p[4] * d, p[5] * d);
            __half2 q3 = __floats2half2_rn(p[6] * d, p[7] * d);
            __half2 q4 = __floats2half2_rn(p[8] * d, p[9] * d);
            uint2* zp = (uint2*)&zs_u[(size_t)ng * PSU];
            zp[0] = make_uint2(*(const unsigned*)&q0, *(const unsigned*)&q1);
            zp[1] = make_uint2(*(const unsigned*)&q2, *(const unsigned*)&q3);
            zp[2] = make_uint2(*(const unsigned*)&q4, 0u);
        }
    }
}

// Push layer 2: one block per 128-node bucket, 256 threads. LDS accum
// [128][12] fp32. 4-lane groups: lane j reads uint2 j of the 24B zs row
// (j==3 spectator; j==2's second half2 is the zero pad -> adds 0 to slots
// 10,11). Epilogue: out[n] = rsqrt(deg+1)*(acc + self) + b2.
__global__ __launch_bounds__(256) void k_push2(
    const uint2* __restrict__ zs2, const unsigned* __restrict__ ebuf,
    const int* __restrict__ bcntg, const int* __restrict__ deg,
    const float* __restrict__ b2, float* __restrict__ out, int n_nodes) {
    __shared__ float zacc[128 * 12];   // 6 KB
    const int tid = threadIdx.x;
    for (int i = tid; i < 128 * 12; i += 256) zacc[i] = 0.f;
    __syncthreads();
    const int b = blockIdx.x, n0 = b << BKSH;
    const int cb = min(bcntg[b], CAP);
    const unsigned* eb = ebuf + (size_t)b * CAP;
    const int l = tid & 63, j = l & 3, gb4 = l & ~3, w = tid >> 6;
    for (int kb = w * 64; kb < cb; kb += 256) {
        unsigned ent_l = (kb + l < cb) ? eb[kb + l] : 0xFFFFFFFFu;
#pragma unroll
        for (int e = 0; e < 4; ++e) {
            unsigned ent = __shfl(ent_l, gb4 + e, 64);
            if (ent == 0xFFFFFFFFu) continue;
            int dl = (int)(ent >> 17), s = (int)(ent & 0x1FFFFu);
            if (j < 3) {
                uint2 v = zs2[(size_t)s * 3 + j];
                float2 fA = __half22float2(*(const __half2*)&v.x);
                float2 fB = __half22float2(*(const __half2*)&v.y);
                float* zr = &zacc[dl * 12 + 4 * j];
                atomicAdd(&zr[0], fA.x); atomicAdd(&zr[1], fA.y);
                atomicAdd(&zr[2], fB.x); atomicAdd(&zr[3], fB.y);
            }
        }
    }
    __syncthreads();
    if (tid < 128) {
        int ng = n0 + tid;
        if (ng < n_nodes) {
            const float d = rsqrtf((float)deg[ng] + 1.0f);
            uint2 z0 = zs2[(size_t)ng * 3 + 0];
            uint2 z1 = zs2[(size_t)ng * 3 + 1];
            uint2 z2 = zs2[(size_t)ng * 3 + 2];
            float2 s0 = __half22float2(*(const __half2*)&z0.x);
            float2 s1 = __half22float2(*(const __half2*)&z0.y);
            float2 s2 = __half22float2(*(const __half2*)&z1.x);
            float2 s3 = __half22float2(*(const __half2*)&z1.y);
            float2 s4 = __half22float2(*(const __half2*)&z2.x);
            const float* zr = &zacc[tid * 12];
            float2* op = (float2*)&out[(size_t)ng * O];
            op[0] = make_float2(fmaf(d, zr[0] + s0.x, b2[0]),
                                fmaf(d, zr[1] + s0.y, b2[1]));
            op[1] = make_float2(fmaf(d, zr[2] + s1.x, b2[2]),
                                fmaf(d, zr[3] + s1.y, b2[3]));
            op[2] = make_float2(fmaf(d, zr[4] + s2.x, b2[4]),
                                fmaf(d, zr[5] + s2.y, b2[5]));
            op[3] = make_float2(fmaf(d, zr[6] + s3.x, b2[6]),
                                fmaf(d, zr[7] + s3.y, b2[7]));
            op[4] = make_float2(fmaf(d, zr[8] + s4.x, b2[8]),
                                fmaf(d, zr[9] + s4.y, b2[9]));
        }
    }
}

static inline size_t align256(size_t v) { return (v + 255) & ~(size_t)255; }

extern "C" void kernel_launch(void* const* d_in, const int* in_sizes, int n_in,
                              void* d_out, int out_size, void* d_ws, size_t ws_size,
                              hipStream_t stream) {
    const float* x  = (const float*)d_in[0];
    const int*   ei = (const int*)d_in[1];
    const float* W1 = (const float*)d_in[2];
    const float* b1 = (const float*)d_in[3];
    const float* W2 = (const float*)d_in[4];
    const float* b2 = (const float*)d_in[5];
    float* out = (float*)d_out;

    const int N = in_sizes[0] / F;   // 100000
    const int E = in_sizes[1] / 2;   // 1600000
    const int* src = ei;
    const int* dst = ei + E;
    const int NBUK = (N + 127) >> BKSH;         // 782

    // Workspace: y[(N+1)*H fp16] | hreg[N*H fp16]: ebuf (NBUK*CAP*4 = 8.0MB)
    // then deg[N] (0.4MB), last 16KB = W1f | zs[(N+1)*PSU uints] | bcntg[1024]
    char* base = (char*)d_ws;
    __half* y = (__half*)base;
    size_t ysz = align256((size_t)(N + 1) * H * 2);
    char* hreg = base + ysz;
    unsigned* ebuf = (unsigned*)hreg;                       // 8.0MB
    int* deg = (int*)(hreg + (size_t)NBUK * CAP * 4);       // +0.4MB = 8.4MB
    __half* W1f = (__half*)(hreg + (size_t)N * H * 2 - (size_t)F * H * 2); // 12.77MB
    size_t hsz = align256((size_t)N * H * 2);
    char* zreg = hreg + hsz;
    unsigned* zs_u = (unsigned*)zreg;
    size_t zsz = align256((size_t)(N + 1) * PSU * 4);
    int* bcntg = (int*)(zreg + zsz);

    const int nbz = (N + 255) / 256;            // 391
    const int nb_bin = (E + EPB - 1) / EPB;     // 391

    k_init<<<nbz + 1 + F * H / 256, 256, 0, stream>>>(deg, bcntg, W1, W1f, N);
    k_bin<<<nb_bin, 256, 0, stream>>>(src, dst, bcntg, deg, ebuf, E);
    k_gemm1<<<(N + 63) / 64, 256, 0, stream>>>(x, W1f, deg, y, N);
    k_push1<<<NBUK, 512, 0, stream>>>((const uint4*)y, ebuf, bcntg, deg,
                                      b1, W2, zs_u, N);
    k_push2<<<NBUK, 256, 0, stream>>>((const uint2*)zs_u, ebuf, bcntg, deg,
                                      b2, out, N);
}

// Round 8
// 245.159 us; speedup vs baseline: 4.0456x; 4.0456x over previous
//
#include <hip/hip_runtime.h>
#include <hip/hip_fp16.h>

// GCN 2-layer forward on gfx950 — CSR-gather with fp16 intermediates (fp32
// accumulation), 8-padded edge lists (dummy node N has all-zero rows), MFMA
// layer-1 transform, W2 projection fused into the layer-1 gather epilogue.
// R17 = R3 (best, 188.9µs) + three proven structural wins:
//  (1) k_bin fuses global deg[] atomics (ran fine inside R7's bin);
//  (2) k_bsort drops its histogram pass — counts come from deg[] (scan-from-
//      deg proven in R14); one fewer ebuf pass + 6.4M fewer LDS atomics;
//  (3) slim-bsort and gemm1 merged into ONE role-split kernel (merge pattern
//      proven to co-execute in R5): gemm1 computes rsqrtf(deg+1) inline
//      (bit-identical to reading dinv[]), so it has no bsort dependency.
// Dataflow lessons locked in: R5 (HBM-random scatter: +113MB write-allocate)
// and R7 (LDS-atomic push: 102M ds_add = 690µs) prove gather-style
// read-duplicate/write-once is the right structure; g1z ~36µs is at its
// delivered-BW roofline (~5.7TB/s for 205MB of random 128B row reads).
// F=128, H=64, O=10. N=100k, E=1.6M.
static constexpr int F = 128;
static constexpr int H = 64;
static constexpr int O = 10;
static constexpr int PSU = 6;          // zs row stride in uints (12 halves, [5]=0 pad)
static constexpr int NBUK_MAX = 256;   // buckets of 512 nodes (dst>>9)
static constexpr int CAP = 12288;      // per-bucket RAW edge capacity (mean 8192, 45σ)
static constexpr int ESCAP = 14336;    // per-bucket PADDED esrc capacity
static constexpr int EPB = 4096;       // edges per block in k_bin
static constexpr int XPAD = 136;       // xh LDS row stride in halves (128 + 8)

typedef _Float16 half8 __attribute__((ext_vector_type(8)));
typedef float floatx4 __attribute__((ext_vector_type(4)));

// blocks 0..390: zero deg; block 391: zero bcntg + dummy rows (y row N,
// zs row N); blocks 392..423: build W1f = fp16 W1 in MFMA B-fragment order.
__global__ __launch_bounds__(256) void k_init(int* __restrict__ deg,
                                              int* __restrict__ bcntg,
                                              const float* __restrict__ W1,
                                              __half* __restrict__ W1f,
                                              unsigned* __restrict__ yN,
                                              unsigned* __restrict__ zsN,
                                              int n_nodes) {
    int b = blockIdx.x, t = threadIdx.x;
    if (b < 391) {
        int i = b * 256 + t;
        if (i < n_nodes) deg[i] = 0;
    } else if (b == 391) {
        bcntg[t] = 0;
        if (t < 32) yN[t] = 0u;      // y row N: 64 halves
        if (t < PSU) zsN[t] = 0u;    // zs row N
    } else {
        int i = (b - 392) * 256 + t;   // 0..8191
        int j = i & 7, lane = (i >> 3) & 63, sc = i >> 9;
        int s = sc >> 2, c = sc & 3;
        int k = s * 32 + (lane >> 4) * 8 + j;
        int nn = c * 16 + (lane & 15);
        W1f[i] = __float2half(W1[k * H + nn]);
    }
}

// Bin edges by bucket = dst>>9; bucket-contiguous packed 4B entries:
// entry = (dst&511)<<17 | src (src < 2^17). Fused: global per-node degree.
__global__ __launch_bounds__(256) void k_bin(const int* __restrict__ src,
                                             const int* __restrict__ dst,
                                             int* __restrict__ bcntg,
                                             int* __restrict__ deg,
                                             unsigned* __restrict__ ebuf, int e_total) {
    __shared__ int hist[NBUK_MAX];
    __shared__ int base[NBUK_MAX];
    __shared__ int loc[NBUK_MAX];
    int t = threadIdx.x;
    hist[t] = 0;
    loc[t] = 0;
    __syncthreads();
    int i0 = blockIdx.x * EPB;
    int i1 = min(i0 + EPB, e_total);
    int i = i0 + 4 * t;
    for (; i + 3 < i1; i += 1024) {
        int4 d4 = *(const int4*)&dst[i];
        atomicAdd(&hist[d4.x >> 9], 1);
        atomicAdd(&hist[d4.y >> 9], 1);
        atomicAdd(&hist[d4.z >> 9], 1);
        atomicAdd(&hist[d4.w >> 9], 1);
        atomicAdd(&deg[d4.x], 1);
        atomicAdd(&deg[d4.y], 1);
        atomicAdd(&deg[d4.z], 1);
        atomicAdd(&deg[d4.w], 1);
    }
    for (; i < i1; ++i) {
        int d = dst[i];
        atomicAdd(&hist[d >> 9], 1);
        atomicAdd(&deg[d], 1);
    }
    __syncthreads();
    if (hist[t] > 0) base[t] = atomicAdd(&bcntg[t], hist[t]);
    __syncthreads();
    i = i0 + 4 * t;
    for (; i + 3 < i1; i += 1024) {
        int4 s4 = *(const int4*)&src[i];
        int4 d4 = *(const int4*)&dst[i];
#pragma unroll
        for (int u = 0; u < 4; ++u) {
            int s = (&s4.x)[u], d = (&d4.x)[u];
            int b = d >> 9;
            int r = base[b] + atomicAdd(&loc[b], 1);
            if (r < CAP)
                ebuf[(size_t)b * CAP + r] = ((unsigned)(d & 511) << 17) | (unsigned)s;
        }
    }
    for (; i < i1; ++i) {
        int s = src[i], d = dst[i];
        int b = d >> 9;
        int r = base[b] + atomicAdd(&loc[b], 1);
        if (r < CAP)
            ebuf[(size_t)b * CAP + r] = ((unsigned)(d & 511) << 17) | (unsigned)s;
    }
}

// Role-split merged kernel.
// Blocks [0, nb_bs): slim bsort — LDS-scan the 8-padded counts taken from
//   deg[] (no histogram pass), scatter src from ebuf into bucket-padded esrc
//   (bucket-major: writes confined to one ~57KB region), pad with dummy N.
//   Emits rowbeg[n], degp[n], dinv[n].
// Blocks [nb_bs, ...): y = fp16((x @ W1) * rsqrt(deg+1)) via MFMA 16x16x32
//   f16, 4 waves = 64 rows — runs concurrently on other CUs (needs only
//   deg from k_bin + W1f from k_init; rsqrtf(deg+1) is bit-identical to the
//   dinv[] value the old gemm1 loaded).
__global__ __launch_bounds__(256, 4) void k_bsg(
    const unsigned* __restrict__ ebuf, const int* __restrict__ bcntg,
    const int* __restrict__ deg, int* __restrict__ rowbeg, int* __restrict__ degp,
    float* __restrict__ dinv, int* __restrict__ esrc,
    const float* __restrict__ x, const __half* __restrict__ W1f,
    __half* __restrict__ y, int n_nodes, int nb_bs) {
    __shared__ __half xh[64 * XPAD];   // gemm path (17.4 KB)
    __shared__ int sa[512];            // bsort path (4 KB)
    __shared__ int sb[512];
    const int tid = threadIdx.x;
    if ((int)blockIdx.x < nb_bs) {     // ---- slim bsort path ----
        const int b = blockIdx.x, n0 = b << 9;
        int cnt[2], cp[2];
#pragma unroll
        for (int u = 0; u < 2; ++u) {
            int ii = tid + 256 * u;
            int n = n0 + ii;
            int c = (n < n_nodes) ? deg[n] : 0;
            cnt[u] = c;
            cp[u] = (c + 7) & ~7;      // 8-padded count
            sa[ii] = cp[u];
        }
        __syncthreads();
        // Hillis-Steele inclusive scan over 512 entries (double-buffered)
        int* A = sa;
        int* Bp = sb;
        for (int off = 1; off < 512; off <<= 1) {
#pragma unroll
            for (int u = 0; u < 2; ++u) {
                int ii = tid + 256 * u;
                int v = A[ii];
                if (ii >= off) v += A[ii - off];
                Bp[ii] = v;
            }
            __syncthreads();
            int* tmp = A; A = Bp; Bp = tmp;
        }
        // A = inclusive scan of padded counts; Bp = free buffer -> cursors
#pragma unroll
        for (int u = 0; u < 2; ++u) {
            int ii = tid + 256 * u;
            int excl = A[ii] - cp[u];
            Bp[ii] = excl;              // scatter cursor (bucket-local)
            int n = n0 + ii;
            if (n < n_nodes) {
                rowbeg[n] = b * ESCAP + excl;
                degp[n] = cp[u];
                dinv[n] = rsqrtf((float)cnt[u] + 1.0f);  // deg + self-loop
            }
        }
        __syncthreads();
        const int cb = min(bcntg[b], CAP);
        const unsigned* eb = ebuf + (size_t)b * CAP;
        int* es = esrc + (size_t)b * ESCAP;
        int i = 4 * tid;
        for (; i + 3 < cb; i += 1024) {
            uint4 e4 = *(const uint4*)&eb[i];
#pragma unroll
            for (int u = 0; u < 4; ++u) {
                unsigned e = (&e4.x)[u];
                int r = atomicAdd(&Bp[e >> 17], 1);
                es[r] = (int)(e & 0x1FFFFu);
            }
        }
        for (; i < cb; ++i) {
            unsigned e = eb[i];
            int r = atomicAdd(&Bp[e >> 17], 1);
            es[r] = (int)(e & 0x1FFFFu);
        }
        __syncthreads();
#pragma unroll
        for (int u = 0; u < 2; ++u) {
            int ii = tid + 256 * u;
            int end = A[ii];                          // excl + padded count
            for (int p = Bp[ii]; p < end; ++p) es[p] = n_nodes;   // dummy pad
        }
        return;
    }
    // ---- gemm path (R3 k_gemm1, dinv inline) ----
    const int lane = tid & 63;
    const int w = tid >> 6;
    const int row0 = ((int)blockIdx.x - nb_bs) * 64;

    half8 bf[16];
    const uint4* wf = (const uint4*)W1f;
#pragma unroll
    for (int sc = 0; sc < 16; ++sc) {
        union { uint4 u; half8 h; } tmp;
        tmp.u = wf[sc * 64 + lane];
        bf[sc] = tmp.h;
    }

    for (int i = tid; i < 64 * 32; i += 256) {
        int r = i >> 5, k4 = i & 31;
        int gr = row0 + r;
        if (gr < n_nodes) {
            float4 v = *(const float4*)&x[(size_t)gr * F + 4 * k4];
            __half2 p0 = __floats2half2_rn(v.x, v.y);
            __half2 p1 = __floats2half2_rn(v.z, v.w);
            uint2 pk = make_uint2(*(unsigned*)&p0, *(unsigned*)&p1);
            *(uint2*)&xh[r * XPAD + 4 * k4] = pk;
        }
    }
    __syncthreads();

    const int m16 = lane & 15, quad = lane >> 4;
    floatx4 acc[4];
#pragma unroll
    for (int c = 0; c < 4; ++c) acc[c] = (floatx4){0.f, 0.f, 0.f, 0.f};
#pragma unroll
    for (int s = 0; s < 4; ++s) {
        union { uint4 u; half8 h; } ua;
        ua.u = *(const uint4*)&xh[(16 * w + m16) * XPAD + s * 32 + quad * 8];
#pragma unroll
        for (int c = 0; c < 4; ++c)
            acc[c] = __builtin_amdgcn_mfma_f32_16x16x32_f16(ua.h, bf[s * 4 + c],
                                                            acc[c], 0, 0, 0);
    }
#pragma unroll
    for (int r = 0; r < 4; ++r) {
        int grow = row0 + 16 * w + quad * 4 + r;
        if (grow < n_nodes) {
            float d = rsqrtf((float)deg[grow] + 1.0f);
#pragma unroll
            for (int c = 0; c < 4; ++c)
                y[(size_t)grow * H + c * 16 + m16] = __float2half(acc[c][r] * d);
        }
    }
}

// Fused layer-1 gather + ReLU + W2 projection (R3-verbatim):
// 8 lanes/node (lane octet c owns features 8c..8c+7), 8 nodes/wave, 32
// nodes/block. uint4 row reads (16B x 8 lanes = full 128B y row); 8 edge
// indices per batch. Epilogue: h = relu(dinv*agg + b1) in regs; per-lane
// partials for all 10 outputs vs W2 transposed in LDS [10][64]; 3-step xor
// fold in the 8-lane group; lane c==0 stores the packed 24B zs row.
__global__ __launch_bounds__(256) void k_gather1z(
    const uint4* __restrict__ yq4, const int* __restrict__ rowbeg,
    const int* __restrict__ degp, const int* __restrict__ esrc,
    const float* __restrict__ dinv, const float* __restrict__ b1,
    const float* __restrict__ W2, unsigned* __restrict__ zs_u, int n_nodes) {
    __shared__ float w2t[O * H];   // 2.56 KB, transposed: w2t[j*64+k] = W2[k*10+j]
    for (int i = threadIdx.x; i < O * H; i += 256)
        w2t[i] = W2[(i & 63) * O + (i >> 6)];
    __syncthreads();
    const int l = threadIdx.x & 63;
    const int c = l & 7;            // feature octet
    const int gbase = l & ~7;       // first lane of this node's group
    const int n = blockIdx.x * 32 + (threadIdx.x >> 3);
    if (n >= n_nodes) return;       // after the only sync: safe
    const int beg = rowbeg[n];
    const int dp = degp[n];
    const float d = dinv[n];

    float acc[8];
    {   // self-loop: whole group adds its own node's row
        uint4 v = yq4[(size_t)n * 8 + c];
        float2 f0 = __half22float2(*(const __half2*)&v.x);
        float2 f1 = __half22float2(*(const __half2*)&v.y);
        float2 f2 = __half22float2(*(const __half2*)&v.z);
        float2 f3 = __half22float2(*(const __half2*)&v.w);
        acc[0] = f0.x; acc[1] = f0.y; acc[2] = f1.x; acc[3] = f1.y;
        acc[4] = f2.x; acc[5] = f2.y; acc[6] = f3.x; acc[7] = f3.y;
    }
    for (int k0 = 0; k0 < dp; k0 += 8) {
        int idx = esrc[beg + k0 + c];    // 8 edges (beg,dp multiples of 8)
#pragma unroll
        for (int e = 0; e < 8; ++e) {
            int s = __shfl(idx, gbase + e, 64);
            uint4 v = yq4[(size_t)s * 8 + c];
            float2 f0 = __half22float2(*(const __half2*)&v.x);
            float2 f1 = __half22float2(*(const __half2*)&v.y);
            float2 f2 = __half22float2(*(const __half2*)&v.z);
            float2 f3 = __half22float2(*(const __half2*)&v.w);
            acc[0] += f0.x; acc[1] += f0.y; acc[2] += f1.x; acc[3] += f1.y;
            acc[4] += f2.x; acc[5] += f2.y; acc[6] += f3.x; acc[7] += f3.y;
        }
    }
    // h (fp32) for this lane's feature octet
    const float4 ba = ((const float4*)b1)[2 * c];
    const float4 bbv = ((const float4*)b1)[2 * c + 1];
    float h[8];
    h[0] = fmaxf(fmaf(d, acc[0], ba.x), 0.0f);
    h[1] = fmaxf(fmaf(d, acc[1], ba.y), 0.0f);
    h[2] = fmaxf(fmaf(d, acc[2], ba.z), 0.0f);
    h[3] = fmaxf(fmaf(d, acc[3], ba.w), 0.0f);
    h[4] = fmaxf(fmaf(d, acc[4], bbv.x), 0.0f);
    h[5] = fmaxf(fmaf(d, acc[5], bbv.y), 0.0f);
    h[6] = fmaxf(fmaf(d, acc[6], bbv.z), 0.0f);
    h[7] = fmaxf(fmaf(d, acc[7], bbv.w), 0.0f);
    // per-lane partials for all 10 outputs (indices compile-time after unroll)
    float p[O];
#pragma unroll
    for (int j = 0; j < O; ++j) {
        float4 wa = *(const float4*)&w2t[j * 64 + 8 * c];
        float4 wb = *(const float4*)&w2t[j * 64 + 8 * c + 4];
        p[j] = h[0] * wa.x + h[1] * wa.y + h[2] * wa.z + h[3] * wa.w
             + h[4] * wb.x + h[5] * wb.y + h[6] * wb.z + h[7] * wb.w;
    }
#pragma unroll
    for (int m = 1; m <= 4; m <<= 1) {      // fold the 8-lane group
#pragma unroll
        for (int j = 0; j < O; ++j) p[j] += __shfl_xor(p[j], m, 64);
    }
    if (c == 0) {
        __half2 q0 = __floats2half2_rn(p[0] * d, p[1] * d);
        __half2 q1 = __floats2half2_rn(p[2] * d, p[3] * d);
        __half2 q2 = __floats2half2_rn(p[4] * d, p[5] * d);
        __half2 q3 = __floats2half2_rn(p[6] * d, p[7] * d);
        __half2 q4 = __floats2half2_rn(p[8] * d, p[9] * d);
        uint2* zp = (uint2*)&zs_u[(size_t)n * PSU];   // n*24B, 8B-aligned
        zp[0] = make_uint2(*(const unsigned*)&q0, *(const unsigned*)&q1);
        zp[1] = make_uint2(*(const unsigned*)&q2, *(const unsigned*)&q3);
        zp[2] = make_uint2(*(const unsigned*)&q4, 0u);   // zero pad uint
    }
}

// out[n][j] = dinv[n] * (zs[n][j] + sum_k zs[esrc[k]][j]) + b2[j]   (fp32 out)
// R3-verbatim: 4 lanes/node, uint2 zs reads (lane j owns output pairs
// {2j,2j+1}); 16 nodes/wave. Lane 3 is a spectator (no fold exists, its
// accumulator is never written).
__global__ __launch_bounds__(256) void k_gather2(
    const unsigned* __restrict__ zs_u, const int* __restrict__ rowbeg,
    const int* __restrict__ degp, const int* __restrict__ esrc,
    const float* __restrict__ dinv, const float* __restrict__ b2,
    float* __restrict__ out, int n_nodes) {
    const int l = threadIdx.x & 63;
    const int j = l & 3;
    const int gb = l & ~3;
    const int jj = (j < 3) ? j : 2;         // lane 3: spectator (dup of slot 2)
    const int n = blockIdx.x * 64 + (threadIdx.x >> 2);
    if (n >= n_nodes) return;
    const int beg = rowbeg[n];
    const int dp = degp[n];
    uint2 v0 = *(const uint2*)&zs_u[(size_t)n * PSU + 2 * jj];
    float2 accA = __half22float2(*(const __half2*)&v0.x);
    float2 accB = __half22float2(*(const __half2*)&v0.y);
    for (int k0 = 0; k0 < dp; k0 += 8) {
        int2 idx = *(const int2*)&esrc[beg + k0 + 2 * j];   // 8 edges (8B-aligned)
#pragma unroll
        for (int e = 0; e < 8; ++e) {
            int s = __shfl((e & 1) ? idx.y : idx.x, gb + (e >> 1), 64);
            uint2 v = *(const uint2*)&zs_u[(size_t)s * PSU + 2 * jj];
            float2 fA = __half22float2(*(const __half2*)&v.x);
            float2 fB = __half22float2(*(const __half2*)&v.y);
            accA.x += fA.x; accA.y += fA.y;
            accB.x += fB.x; accB.y += fB.y;
        }
    }
    if (j < 3) {
        const float d = dinv[n];
        float2 bbA = ((const float2*)b2)[2 * j];
        float2 oA = make_float2(fmaf(d, accA.x, bbA.x), fmaf(d, accA.y, bbA.y));
        *(float2*)&out[(size_t)n * O + 4 * j] = oA;       // outputs 4j,4j+1
        if (j < 2) {
            float2 bbB = ((const float2*)b2)[2 * j + 1];
            float2 oB = make_float2(fmaf(d, accB.x, bbB.x), fmaf(d, accB.y, bbB.y));
            *(float2*)&out[(size_t)n * O + 4 * j + 2] = oB;   // outputs 4j+2,4j+3
        }
    }
}

static inline size_t align256(size_t v) { return (v + 255) & ~(size_t)255; }

extern "C" void kernel_launch(void* const* d_in, const int* in_sizes, int n_in,
                              void* d_out, int out_size, void* d_ws, size_t ws_size,
                              hipStream_t stream) {
    const float* x  = (const float*)d_in[0];
    const int*   ei = (const int*)d_in[1];
    const float* W1 = (const float*)d_in[2];
    const float* b1 = (const float*)d_in[3];
    const float* W2 = (const float*)d_in[4];
    const float* b2 = (const float*)d_in[5];
    float* out = (float*)d_out;

    const int N = in_sizes[0] / F;   // 100000
    const int E = in_sizes[1] / 2;   // 1600000
    const int* src = ei;
    const int* dst = ei + E;
    const int NBUK = (N + 511) >> 9;            // 196

    // Workspace: y[(N+1)*H fp16] | hreg[N*H fp16]: ebuf (9.63MB) then deg[N]
    // (0.4MB), last 16KB = W1f | zs[(N+1)*PSU uints] | dinv[N] | rowbeg[N]
    // | degp[N] | bcntg[256] | esrc[NBUK*ESCAP + 64]
    char* base = (char*)d_ws;
    __half* y = (__half*)base;
    size_t ysz = align256((size_t)(N + 1) * H * 2);
    char* hreg = base + ysz;
    unsigned* ebuf = (unsigned*)hreg;                       // 9.63MB
    int* deg = (int*)(hreg + (size_t)NBUK * CAP * 4);       // +0.4MB = 10.03MB
    __half* W1f = (__half*)(hreg + (size_t)N * H * 2 - (size_t)F * H * 2);
    size_t hsz = align256((size_t)N * H * 2);
    char* zreg = hreg + hsz;
    unsigned* zs_u = (unsigned*)zreg;
    size_t zsz = align256((size_t)(N + 1) * PSU * 4);
    float* dinv = (float*)(zreg + zsz);
    int* rowbeg = (int*)(dinv + N);
    int* degp = rowbeg + N;
    int* bcntg = degp + N;
    int* esrc = bcntg + 256;

    const int nb_bin = (E + EPB - 1) / EPB;     // 391
    const int NB_GM = (N + 63) / 64;            // 1563 gemm blocks

    k_init<<<392 + F * H / 256, 256, 0, stream>>>(deg, bcntg, W1, W1f,
                                                  (unsigned*)(y + (size_t)N * H),
                                                  zs_u + (size_t)N * PSU, N);
    k_bin<<<nb_bin, 256, 0, stream>>>(src, dst, bcntg, deg, ebuf, E);
    k_bsg<<<NBUK + NB_GM, 256, 0, stream>>>(ebuf, bcntg, deg, rowbeg, degp,
                                            dinv, esrc, x, W1f, y, N, NBUK);
    k_gather1z<<<(N + 31) / 32, 256, 0, stream>>>((const uint4*)y, rowbeg, degp,
                                                  esrc, dinv, b1, W2, zs_u, N);
    k_gather2<<<(N + 63) / 64, 256, 0, stream>>>(zs_u, rowbeg, degp, esrc,
                                                 dinv, b2, out, N);
}

// Round 9
// 193.554 us; speedup vs baseline: 5.1242x; 1.2666x over previous
//
#include <hip/hip_runtime.h>
#include <hip/hip_fp16.h>

// GCN 2-layer forward on gfx950 — CSR-gather with fp16 intermediates (fp32
// accumulation), 8-padded edge lists (dummy node N has all-zero rows), MFMA
// layer-1 transform, W2 projection fused into the layer-1 gather epilogue.
// R19 = R3 (best, 188.9µs) + ONE change: y is stored UNSCALED (fp16(x@W1)),
// with the per-source dinv[s] applied in gather1z as an fma (dv shuffled
// beside idx; fp16 relative error is scale-invariant -> same numerics class).
// This breaks the dinv->gemm dependency, so gemm1 merges role-split with
// k_bin (co-execution proven R5/R8). No deg array, NO global atomics:
// R8 measured 1.6M device-scope atomics on a 400KB array = 82µs k_bin
// (cross-XCD line ping-pong, +51MB HBM write) — LDS-histogram only.
// Other locked lessons: R5 edge-major scatter = +113MB write-allocate;
// R7 LDS-atomic push = 690µs; R3/R4: gathers are y-row-BW-bound (~36µs
// at ~5.7TB/s delivered = roofline), pads/MLP-staging are free.
// F=128, H=64, O=10. N=100k, E=1.6M.
static constexpr int F = 128;
static constexpr int H = 64;
static constexpr int O = 10;
static constexpr int PSU = 6;          // zs row stride in uints (12 halves, [5]=0 pad)
static constexpr int NBUK_MAX = 256;   // buckets of 512 nodes (dst>>9)
static constexpr int CAP = 12288;      // per-bucket RAW edge capacity (mean 8192, 45σ)
static constexpr int ESCAP = 14336;    // per-bucket PADDED esrc capacity
static constexpr int EPB = 4096;       // edges per block in k_bin path
static constexpr int XPAD = 136;       // xh LDS row stride in halves (128 + 8)

typedef _Float16 half8 __attribute__((ext_vector_type(8)));
typedef float floatx4 __attribute__((ext_vector_type(4)));

// block 0: zero bcntg + zero dummy rows (y row N, zs row N);
// blocks 1..32: build W1f = fp16 W1 in MFMA B-fragment order.
__global__ __launch_bounds__(256) void k_init(int* __restrict__ bcntg,
                                              const float* __restrict__ W1,
                                              __half* __restrict__ W1f,
                                              unsigned* __restrict__ yN,
                                              unsigned* __restrict__ zsN) {
    int b = blockIdx.x, t = threadIdx.x;
    if (b == 0) {
        bcntg[t] = 0;
        if (t < 32) yN[t] = 0u;      // y row N: 64 halves
        if (t < PSU) zsN[t] = 0u;    // zs row N
    } else {
        int i = (b - 1) * 256 + t;   // 0..8191
        int j = i & 7, lane = (i >> 3) & 63, sc = i >> 9;
        int s = sc >> 2, c = sc & 3;
        int k = s * 32 + (lane >> 4) * 8 + j;
        int nn = c * 16 + (lane & 15);
        W1f[i] = __float2half(W1[k * H + nn]);
    }
}

// Role-split merged kernel (no data dependency between the two paths).
// Blocks [0, nb_bin): R3 k_bin verbatim — bin edges by bucket = dst>>9 into
//   bucket-contiguous packed entries (dst&511)<<17 | src, two-level cursors
//   (LDS hist + one global add per block per bucket). LDS atomics only.
// Blocks [nb_bin, ...): y = fp16(x @ W1) UNSCALED via MFMA 16x16x32 f16,
//   4 waves = 64 rows/block (needs only W1f from k_init + x).
__global__ __launch_bounds__(256, 4) void k_bingemm(
    const int* __restrict__ src, const int* __restrict__ dst,
    int* __restrict__ bcntg, unsigned* __restrict__ ebuf, int e_total,
    const float* __restrict__ x, const __half* __restrict__ W1f,
    __half* __restrict__ y, int n_nodes, int nb_bin) {
    __shared__ __half xh[64 * XPAD];   // gemm path (17.4 KB)
    __shared__ int hist[NBUK_MAX];     // bin path (3 KB)
    __shared__ int base[NBUK_MAX];
    __shared__ int loc[NBUK_MAX];
    const int t = threadIdx.x;
    if ((int)blockIdx.x < nb_bin) {    // ---- bin path (R3-verbatim) ----
        hist[t] = 0;
        loc[t] = 0;
        __syncthreads();
        int i0 = blockIdx.x * EPB;
        int i1 = min(i0 + EPB, e_total);
        int i = i0 + 4 * t;
        for (; i + 3 < i1; i += 1024) {
            int4 d4 = *(const int4*)&dst[i];
            atomicAdd(&hist[d4.x >> 9], 1);
            atomicAdd(&hist[d4.y >> 9], 1);
            atomicAdd(&hist[d4.z >> 9], 1);
            atomicAdd(&hist[d4.w >> 9], 1);
        }
        for (; i < i1; ++i) atomicAdd(&hist[dst[i] >> 9], 1);
        __syncthreads();
        if (hist[t] > 0) base[t] = atomicAdd(&bcntg[t], hist[t]);
        __syncthreads();
        i = i0 + 4 * t;
        for (; i + 3 < i1; i += 1024) {
            int4 s4 = *(const int4*)&src[i];
            int4 d4 = *(const int4*)&dst[i];
#pragma unroll
            for (int u = 0; u < 4; ++u) {
                int s = (&s4.x)[u], d = (&d4.x)[u];
                int b = d >> 9;
                int r = base[b] + atomicAdd(&loc[b], 1);
                if (r < CAP)
                    ebuf[(size_t)b * CAP + r] = ((unsigned)(d & 511) << 17) | (unsigned)s;
            }
        }
        for (; i < i1; ++i) {
            int s = src[i], d = dst[i];
            int b = d >> 9;
            int r = base[b] + atomicAdd(&loc[b], 1);
            if (r < CAP)
                ebuf[(size_t)b * CAP + r] = ((unsigned)(d & 511) << 17) | (unsigned)s;
        }
        return;
    }
    // ---- gemm path (R3 k_gemm1, UNSCALED store) ----
    const int lane = t & 63;
    const int w = t >> 6;
    const int row0 = ((int)blockIdx.x - nb_bin) * 64;

    half8 bf[16];
    const uint4* wf = (const uint4*)W1f;
#pragma unroll
    for (int sc = 0; sc < 16; ++sc) {
        union { uint4 u; half8 h; } tmp;
        tmp.u = wf[sc * 64 + lane];
        bf[sc] = tmp.h;
    }

    for (int i = t; i < 64 * 32; i += 256) {
        int r = i >> 5, k4 = i & 31;
        int gr = row0 + r;
        if (gr < n_nodes) {
            float4 v = *(const float4*)&x[(size_t)gr * F + 4 * k4];
            __half2 p0 = __floats2half2_rn(v.x, v.y);
            __half2 p1 = __floats2half2_rn(v.z, v.w);
            uint2 pk = make_uint2(*(unsigned*)&p0, *(unsigned*)&p1);
            *(uint2*)&xh[r * XPAD + 4 * k4] = pk;
        }
    }
    __syncthreads();

    const int m16 = lane & 15, quad = lane >> 4;
    floatx4 acc[4];
#pragma unroll
    for (int c = 0; c < 4; ++c) acc[c] = (floatx4){0.f, 0.f, 0.f, 0.f};
#pragma unroll
    for (int s = 0; s < 4; ++s) {
        union { uint4 u; half8 h; } ua;
        ua.u = *(const uint4*)&xh[(16 * w + m16) * XPAD + s * 32 + quad * 8];
#pragma unroll
        for (int c = 0; c < 4; ++c)
            acc[c] = __builtin_amdgcn_mfma_f32_16x16x32_f16(ua.h, bf[s * 4 + c],
                                                            acc[c], 0, 0, 0);
    }
#pragma unroll
    for (int r = 0; r < 4; ++r) {
        int grow = row0 + 16 * w + quad * 4 + r;
        if (grow < n_nodes) {
#pragma unroll
            for (int c = 0; c < 4; ++c)
                y[(size_t)grow * H + c * 16 + m16] = __float2half(acc[c][r]);
        }
    }
}

// One block per bucket (R3-verbatim + dinv[N]=0 for pad edges): count
// in-degrees (LDS), LDS-scan 8-padded counts, scatter src into bucket-padded
// esrc (stride ESCAP), pad with dummy node N. Emits rowbeg, degp, dinv.
__global__ __launch_bounds__(256) void k_bsort(
    const unsigned* __restrict__ ebuf, const int* __restrict__ bcntg,
    int* __restrict__ rowbeg, int* __restrict__ degp, float* __restrict__ dinv,
    int* __restrict__ esrc, int n_nodes) {
    __shared__ int hc[512];
    __shared__ int sa[512];
    __shared__ int sb[512];
    int t = threadIdx.x, b = blockIdx.x, n0 = b << 9;
    if (b == 0 && t == 0) dinv[n_nodes] = 0.0f;   // pad edges: 0 * y_N(=0)
    hc[t] = 0;
    hc[t + 256] = 0;
    __syncthreads();
    int cb = min(bcntg[b], CAP);
    const unsigned* eb = ebuf + (size_t)b * CAP;
    int i = 4 * t;
    for (; i + 3 < cb; i += 1024) {
        uint4 e4 = *(const uint4*)&eb[i];
        atomicAdd(&hc[e4.x >> 17], 1);
        atomicAdd(&hc[e4.y >> 17], 1);
        atomicAdd(&hc[e4.z >> 17], 1);
        atomicAdd(&hc[e4.w >> 17], 1);
    }
    for (; i < cb; ++i) atomicAdd(&hc[eb[i] >> 17], 1);
    __syncthreads();
#pragma unroll
    for (int u = 0; u < 2; ++u) {
        int ii = t + 256 * u;
        sa[ii] = (hc[ii] + 7) & ~7;     // 8-padded count
    }
    __syncthreads();
    // Hillis-Steele inclusive scan over 512 entries (double-buffered)
    int* A = sa;
    int* Bp = sb;
    for (int off = 1; off < 512; off <<= 1) {
#pragma unroll
        for (int u = 0; u < 2; ++u) {
            int ii = t + 256 * u;
            int v = A[ii];
            if (ii >= off) v += A[ii - off];
            Bp[ii] = v;
        }
        __syncthreads();
        int* tmp = A; A = Bp; Bp = tmp;
    }
    // A = inclusive scan of padded counts; Bp = free buffer -> cursors
#pragma unroll
    for (int u = 0; u < 2; ++u) {
        int ii = t + 256 * u;
        int cnt = hc[ii];
        int cp = (cnt + 7) & ~7;
        int excl = A[ii] - cp;
        Bp[ii] = excl;                  // scatter cursor (bucket-local)
        int n = n0 + ii;
        if (n < n_nodes) {
            rowbeg[n] = b * ESCAP + excl;
            degp[n] = cp;
            dinv[n] = rsqrtf((float)cnt + 1.0f);   // true degree + self-loop
        }
    }
    __syncthreads();
    int* es = esrc + (size_t)b * ESCAP;
    i = 4 * t;
    for (; i + 3 < cb; i += 1024) {
        uint4 e4 = *(const uint4*)&eb[i];
#pragma unroll
        for (int u = 0; u < 4; ++u) {
            unsigned e = (&e4.x)[u];
            int r = atomicAdd(&Bp[e >> 17], 1);
            es[r] = (int)(e & 0x1FFFFu);
        }
    }
    for (; i < cb; ++i) {
        unsigned e = eb[i];
        int r = atomicAdd(&Bp[e >> 17], 1);
        es[r] = (int)(e & 0x1FFFFu);
    }
    __syncthreads();
#pragma unroll
    for (int u = 0; u < 2; ++u) {
        int ii = t + 256 * u;
        int end = A[ii];                          // excl + padded count
        for (int p = Bp[ii]; p < end; ++p) es[p] = n_nodes;   // dummy pad
    }
}

// Fused layer-1 gather + ReLU + W2 projection:
// 8 lanes/node (lane octet c owns features 8c..8c+7), 8 nodes/wave, 32
// nodes/block. uint4 row reads (16B x 8 lanes = full 128B y row). y is
// UNSCALED, so each edge accumulates fmaf(f, dinv[s], acc) — lane c loads
// dvl = dinv[idx] (L2-hit) beside its edge index and the group shuffles
// both. Self-loop seeds acc = f * dinv[n]. Pad edges: y row N = 0 AND
// dinv[N] = 0 (no NaN). Epilogue: h = relu(dinv*acc + b1); per-lane W2
// partials vs w2t [10][64] in LDS; 3-step xor fold; lane c==0 stores the
// packed 24B zs row (zs = dinv[n] * (h @ W2), identical to R3).
__global__ __launch_bounds__(256) void k_gather1z(
    const uint4* __restrict__ yq4, const int* __restrict__ rowbeg,
    const int* __restrict__ degp, const int* __restrict__ esrc,
    const float* __restrict__ dinv, const float* __restrict__ b1,
    const float* __restrict__ W2, unsigned* __restrict__ zs_u, int n_nodes) {
    __shared__ float w2t[O * H];   // 2.56 KB, transposed: w2t[j*64+k] = W2[k*10+j]
    for (int i = threadIdx.x; i < O * H; i += 256)
        w2t[i] = W2[(i & 63) * O + (i >> 6)];
    __syncthreads();
    const int l = threadIdx.x & 63;
    const int c = l & 7;            // feature octet
    const int gbase = l & ~7;       // first lane of this node's group
    const int n = blockIdx.x * 32 + (threadIdx.x >> 3);
    if (n >= n_nodes) return;       // after the only sync: safe
    const int beg = rowbeg[n];
    const int dp = degp[n];
    const float d = dinv[n];

    float acc[8];
    {   // self-loop: whole group adds its own node's row, scaled by dinv[n]
        uint4 v = yq4[(size_t)n * 8 + c];
        float2 f0 = __half22float2(*(const __half2*)&v.x);
        float2 f1 = __half22float2(*(const __half2*)&v.y);
        float2 f2 = __half22float2(*(const __half2*)&v.z);
        float2 f3 = __half22float2(*(const __half2*)&v.w);
        acc[0] = f0.x * d; acc[1] = f0.y * d; acc[2] = f1.x * d; acc[3] = f1.y * d;
        acc[4] = f2.x * d; acc[5] = f2.y * d; acc[6] = f3.x * d; acc[7] = f3.y * d;
    }
    for (int k0 = 0; k0 < dp; k0 += 8) {
        int idx = esrc[beg + k0 + c];    // 8 edges (beg,dp multiples of 8)
        float dvl = dinv[idx];           // source-node scale (L2-hit)
#pragma unroll
        for (int e = 0; e < 8; ++e) {
            int s = __shfl(idx, gbase + e, 64);
            float dv = __shfl(dvl, gbase + e, 64);
            uint4 v = yq4[(size_t)s * 8 + c];
            float2 f0 = __half22float2(*(const __half2*)&v.x);
            float2 f1 = __half22float2(*(const __half2*)&v.y);
            float2 f2 = __half22float2(*(const __half2*)&v.z);
            float2 f3 = __half22float2(*(const __half2*)&v.w);
            acc[0] = fmaf(f0.x, dv, acc[0]); acc[1] = fmaf(f0.y, dv, acc[1]);
            acc[2] = fmaf(f1.x, dv, acc[2]); acc[3] = fmaf(f1.y, dv, acc[3]);
            acc[4] = fmaf(f2.x, dv, acc[4]); acc[5] = fmaf(f2.y, dv, acc[5]);
            acc[6] = fmaf(f3.x, dv, acc[6]); acc[7] = fmaf(f3.y, dv, acc[7]);
        }
    }
    // h (fp32) for this lane's feature octet
    const float4 ba = ((const float4*)b1)[2 * c];
    const float4 bbv = ((const float4*)b1)[2 * c + 1];
    float h[8];
    h[0] = fmaxf(fmaf(d, acc[0], ba.x), 0.0f);
    h[1] = fmaxf(fmaf(d, acc[1], ba.y), 0.0f);
    h[2] = fmaxf(fmaf(d, acc[2], ba.z), 0.0f);
    h[3] = fmaxf(fmaf(d, acc[3], ba.w), 0.0f);
    h[4] = fmaxf(fmaf(d, acc[4], bbv.x), 0.0f);
    h[5] = fmaxf(fmaf(d, acc[5], bbv.y), 0.0f);
    h[6] = fmaxf(fmaf(d, acc[6], bbv.z), 0.0f);
    h[7] = fmaxf(fmaf(d, acc[7], bbv.w), 0.0f);
    // per-lane partials for all 10 outputs (indices compile-time after unroll)
    float p[O];
#pragma unroll
    for (int j = 0; j < O; ++j) {
        float4 wa = *(const float4*)&w2t[j * 64 + 8 * c];
        float4 wb = *(const float4*)&w2t[j * 64 + 8 * c + 4];
        p[j] = h[0] * wa.x + h[1] * wa.y + h[2] * wa.z + h[3] * wa.w
             + h[4] * wb.x + h[5] * wb.y + h[6] * wb.z + h[7] * wb.w;
    }
#pragma unroll
    for (int m = 1; m <= 4; m <<= 1) {      // fold the 8-lane group
#pragma unroll
        for (int j = 0; j < O; ++j) p[j] += __shfl_xor(p[j], m, 64);
    }
    if (c == 0) {
        __half2 q0 = __floats2half2_rn(p[0] * d, p[1] * d);
        __half2 q1 = __floats2half2_rn(p[2] * d, p[3] * d);
        __half2 q2 = __floats2half2_rn(p[4] * d, p[5] * d);
        __half2 q3 = __floats2half2_rn(p[6] * d, p[7] * d);
        __half2 q4 = __floats2half2_rn(p[8] * d, p[9] * d);
        uint2* zp = (uint2*)&zs_u[(size_t)n * PSU];   // n*24B, 8B-aligned
        zp[0] = make_uint2(*(const unsigned*)&q0, *(const unsigned*)&q1);
        zp[1] = make_uint2(*(const unsigned*)&q2, *(const unsigned*)&q3);
        zp[2] = make_uint2(*(const unsigned*)&q4, 0u);   // zero pad uint
    }
}

// out[n][j] = dinv[n] * (zs[n][j] + sum_k zs[esrc[k]][j]) + b2[j]   (fp32 out)
// R3-verbatim: 4 lanes/node, uint2 zs reads (lane j owns output pairs
// {2j,2j+1}); 16 nodes/wave. Lane 3 is a spectator (no fold exists, its
// accumulator is never written). zs rows are pre-scaled by dinv[src].
__global__ __launch_bounds__(256) void k_gather2(
    const unsigned* __restrict__ zs_u, const int* __restrict__ rowbeg,
    const int* __restrict__ degp, const int* __restrict__ esrc,
    const float* __restrict__ dinv, const float* __restrict__ b2,
    float* __restrict__ out, int n_nodes) {
    const int l = threadIdx.x & 63;
    const int j = l & 3;
    const int gb = l & ~3;
    const int jj = (j < 3) ? j : 2;         // lane 3: spectator (dup of slot 2)
    const int n = blockIdx.x * 64 + (threadIdx.x >> 2);
    if (n >= n_nodes) return;
    const int beg = rowbeg[n];
    const int dp = degp[n];
    uint2 v0 = *(const uint2*)&zs_u[(size_t)n * PSU + 2 * jj];
    float2 accA = __half22float2(*(const __half2*)&v0.x);
    float2 accB = __half22float2(*(const __half2*)&v0.y);
    for (int k0 = 0; k0 < dp; k0 += 8) {
        int2 idx = *(const int2*)&esrc[beg + k0 + 2 * j];   // 8 edges (8B-aligned)
#pragma unroll
        for (int e = 0; e < 8; ++e) {
            int s = __shfl((e & 1) ? idx.y : idx.x, gb + (e >> 1), 64);
            uint2 v = *(const uint2*)&zs_u[(size_t)s * PSU + 2 * jj];
            float2 fA = __half22float2(*(const __half2*)&v.x);
            float2 fB = __half22float2(*(const __half2*)&v.y);
            accA.x += fA.x; accA.y += fA.y;
            accB.x += fB.x; accB.y += fB.y;
        }
    }
    if (j < 3) {
        const float d = dinv[n];
        float2 bbA = ((const float2*)b2)[2 * j];
        float2 oA = make_float2(fmaf(d, accA.x, bbA.x), fmaf(d, accA.y, bbA.y));
        *(float2*)&out[(size_t)n * O + 4 * j] = oA;       // outputs 4j,4j+1
        if (j < 2) {
            float2 bbB = ((const float2*)b2)[2 * j + 1];
            float2 oB = make_float2(fmaf(d, accB.x, bbB.x), fmaf(d, accB.y, bbB.y));
            *(float2*)&out[(size_t)n * O + 4 * j + 2] = oB;   // outputs 4j+2,4j+3
        }
    }
}

static inline size_t align256(size_t v) { return (v + 255) & ~(size_t)255; }

extern "C" void kernel_launch(void* const* d_in, const int* in_sizes, int n_in,
                              void* d_out, int out_size, void* d_ws, size_t ws_size,
                              hipStream_t stream) {
    const float* x  = (const float*)d_in[0];
    const int*   ei = (const int*)d_in[1];
    const float* W1 = (const float*)d_in[2];
    const float* b1 = (const float*)d_in[3];
    const float* W2 = (const float*)d_in[4];
    const float* b2 = (const float*)d_in[5];
    float* out = (float*)d_out;

    const int N = in_sizes[0] / F;   // 100000
    const int E = in_sizes[1] / 2;   // 1600000
    const int* src = ei;
    const int* dst = ei + E;
    const int NBUK = (N + 511) >> 9;            // 196

    // Workspace (R3 layout, dinv widened to N+1): y[(N+1)*H fp16] | hreg
    // [N*H fp16] (front aliased by ebuf 9.63MB, consumed by k_bsort; last
    // 16KB = W1f) | zs[(N+1)*PSU uints] | dinv[N+1] | rowbeg[N] | degp[N]
    // | bcntg[256] | esrc[NBUK*ESCAP + 64]
    char* base = (char*)d_ws;
    __half* y = (__half*)base;
    size_t ysz = align256((size_t)(N + 1) * H * 2);
    char* hreg = base + ysz;
    unsigned* ebuf = (unsigned*)hreg;                       // 9.63MB <= 12.78MB
    __half* W1f = (__half*)(hreg + (size_t)N * H * 2 - (size_t)F * H * 2);
    size_t hsz = align256((size_t)N * H * 2);
    char* zreg = hreg + hsz;
    unsigned* zs_u = (unsigned*)zreg;
    size_t zsz = align256((size_t)(N + 1) * PSU * 4);
    float* dinv = (float*)(zreg + zsz);
    int* rowbeg = (int*)(dinv + N + 1);
    int* degp = rowbeg + N;
    int* bcntg = degp + N;
    int* esrc = bcntg + 256;

    const int NB_BIN = (E + EPB - 1) / EPB;     // 391
    const int NB_GM = (N + 63) / 64;            // 1563

    k_init<<<1 + F * H / 256, 256, 0, stream>>>(bcntg, W1, W1f,
                                                (unsigned*)(y + (size_t)N * H),
                                                zs_u + (size_t)N * PSU);
    k_bingemm<<<NB_BIN + NB_GM, 256, 0, stream>>>(src, dst, bcntg, ebuf, E,
                                                  x, W1f, y, N, NB_BIN);
    k_bsort<<<NBUK, 256, 0, stream>>>(ebuf, bcntg, rowbeg, degp, dinv, esrc, N);
    k_gather1z<<<(N + 31) / 32, 256, 0, stream>>>((const uint4*)y, rowbeg, degp,
                                                  esrc, dinv, b1, W2, zs_u, N);
    k_gather2<<<(N + 63) / 64, 256, 0, stream>>>(zs_u, rowbeg, degp, esrc,
                                                 dinv, b2, out, N);
}

// Round 10
// 190.574 us; speedup vs baseline: 5.2043x; 1.0156x over previous
//
#include <hip/hip_runtime.h>
#include <hip/hip_fp16.h>

// GCN 2-layer forward on gfx950 — CSR-gather with fp16 intermediates (fp32
// accumulation), single-kernel bucketed CSR build with 8-padded edge lists
// (dummy node N has all-zero rows), MFMA layer-1 transform, W2 projection
// fused into the layer-1 gather epilogue (h never materializes).
// R20 = R3 verbatim (best verified: 188.9µs). Final revert after R4-R9
// explored and falsified every alternative, each with counter evidence:
//  - R4 MLP staging/prefetch: null (gathers are BW-bound, not latency-bound)
//  - R5 edge-major direct scatter: 99µs (random 4B writes -> +113MB HBM
//    write-allocate; scatter must be bucket-major)
//  - R7 LDS-atomic push: 690µs (102M ds_add_f32 serialize the LDS pipe)
//  - R8 global-atomic degree count: k_bin 82µs (1.6M device-scope atomics
//    on a 400KB array ping-pong lines across 8 non-coherent XCD L2s)
//  - R9 bin∥gemm role-split merge: 45.6µs > 18+12 serial (merging an
//    atomic-bound phase with an LDS/MFMA phase loses occupancy arbitration)
// Remaining budget at 188.9µs: ~84µs harness poison-fills (fixed) + ~105µs
// kernels, of which gather1z ~36µs at ~5.7TB/s delivered random-128B-row
// bandwidth (roofline) and gather2 its L2-resident analog.
// F=128, H=64, O=10. N=100k, E=1.6M.
static constexpr int F = 128;
static constexpr int H = 64;
static constexpr int O = 10;
static constexpr int PSU = 6;          // zs row stride in uints (12 halves, [5]=0 pad)
static constexpr int NBUK_MAX = 256;   // buckets of 512 nodes (dst>>9)
static constexpr int CAP = 12288;      // per-bucket RAW edge capacity (mean 8192, 45σ)
static constexpr int ESCAP = 14336;    // per-bucket PADDED esrc capacity
                                       // (pad-8 mean ~10.45k, huge headroom)
static constexpr int EPB = 4096;       // edges per block in k_bin
static constexpr int XPAD = 136;       // xh LDS row stride in halves (128 + 8)

typedef _Float16 half8 __attribute__((ext_vector_type(8)));
typedef float floatx4 __attribute__((ext_vector_type(4)));

// block 0: zero bcntg + zero dummy rows (y row N, zs row N);
// blocks 1..32: build W1f = fp16 W1 in MFMA B-fragment order.
__global__ __launch_bounds__(256) void k_init(int* __restrict__ bcntg,
                                              const float* __restrict__ W1,
                                              __half* __restrict__ W1f,
                                              unsigned* __restrict__ yN,
                                              unsigned* __restrict__ zsN) {
    int b = blockIdx.x, t = threadIdx.x;
    if (b == 0) {
        bcntg[t] = 0;
        if (t < 32) yN[t] = 0u;      // y row N: 64 halves
        if (t < PSU) zsN[t] = 0u;    // zs row N
    } else {
        int i = (b - 1) * 256 + t;   // 0..8191
        int j = i & 7, lane = (i >> 3) & 63, sc = i >> 9;
        int s = sc >> 2, c = sc & 3;
        int k = s * 32 + (lane >> 4) * 8 + j;
        int nn = c * 16 + (lane & 15);
        W1f[i] = __float2half(W1[k * H + nn]);
    }
}

// Bin edges by bucket = dst>>9; bucket-contiguous packed 4B entries:
// entry = (dst&511)<<17 | src   (src < 2^17).
__global__ __launch_bounds__(256) void k_bin(const int* __restrict__ src,
                                             const int* __restrict__ dst,
                                             int* __restrict__ bcntg,
                                             unsigned* __restrict__ ebuf, int e_total) {
    __shared__ int hist[NBUK_MAX];
    __shared__ int base[NBUK_MAX];
    __shared__ int loc[NBUK_MAX];
    int t = threadIdx.x;
    hist[t] = 0;
    loc[t] = 0;
    __syncthreads();
    int i0 = blockIdx.x * EPB;
    int i1 = min(i0 + EPB, e_total);
    int i = i0 + 4 * t;
    for (; i + 3 < i1; i += 1024) {
        int4 d4 = *(const int4*)&dst[i];
        atomicAdd(&hist[d4.x >> 9], 1);
        atomicAdd(&hist[d4.y >> 9], 1);
        atomicAdd(&hist[d4.z >> 9], 1);
        atomicAdd(&hist[d4.w >> 9], 1);
    }
    for (; i < i1; ++i) atomicAdd(&hist[dst[i] >> 9], 1);
    __syncthreads();
    if (hist[t] > 0) base[t] = atomicAdd(&bcntg[t], hist[t]);
    __syncthreads();
    i = i0 + 4 * t;
    for (; i + 3 < i1; i += 1024) {
        int4 s4 = *(const int4*)&src[i];
        int4 d4 = *(const int4*)&dst[i];
#pragma unroll
        for (int u = 0; u < 4; ++u) {
            int s = (&s4.x)[u], d = (&d4.x)[u];
            int b = d >> 9;
            int r = base[b] + atomicAdd(&loc[b], 1);
            if (r < CAP)
                ebuf[(size_t)b * CAP + r] = ((unsigned)(d & 511) << 17) | (unsigned)s;
        }
    }
    for (; i < i1; ++i) {
        int s = src[i], d = dst[i];
        int b = d >> 9;
        int r = base[b] + atomicAdd(&loc[b], 1);
        if (r < CAP)
            ebuf[(size_t)b * CAP + r] = ((unsigned)(d & 511) << 17) | (unsigned)s;
    }
}

// One block per bucket: count in-degrees (LDS), LDS-scan 8-padded counts,
// scatter src into bucket-padded esrc (stride ESCAP), pad with dummy node N.
// Emits rowbeg[n] (absolute into esrc), degp[n] (8-padded), dinv[n].
__global__ __launch_bounds__(256) void k_bsort(
    const unsigned* __restrict__ ebuf, const int* __restrict__ bcntg,
    int* __restrict__ rowbeg, int* __restrict__ degp, float* __restrict__ dinv,
    int* __restrict__ esrc, int n_nodes) {
    __shared__ int hc[512];
    __shared__ int sa[512];
    __shared__ int sb[512];
    int t = threadIdx.x, b = blockIdx.x, n0 = b << 9;
    hc[t] = 0;
    hc[t + 256] = 0;
    __syncthreads();
    int cb = min(bcntg[b], CAP);
    const unsigned* eb = ebuf + (size_t)b * CAP;
    int i = 4 * t;
    for (; i + 3 < cb; i += 1024) {
        uint4 e4 = *(const uint4*)&eb[i];
        atomicAdd(&hc[e4.x >> 17], 1);
        atomicAdd(&hc[e4.y >> 17], 1);
        atomicAdd(&hc[e4.z >> 17], 1);
        atomicAdd(&hc[e4.w >> 17], 1);
    }
    for (; i < cb; ++i) atomicAdd(&hc[eb[i] >> 17], 1);
    __syncthreads();
#pragma unroll
    for (int u = 0; u < 2; ++u) {
        int ii = t + 256 * u;
        sa[ii] = (hc[ii] + 7) & ~7;     // 8-padded count
    }
    __syncthreads();
    // Hillis-Steele inclusive scan over 512 entries (double-buffered)
    int* A = sa;
    int* Bp = sb;
    for (int off = 1; off < 512; off <<= 1) {
#pragma unroll
        for (int u = 0; u < 2; ++u) {
            int ii = t + 256 * u;
            int v = A[ii];
            if (ii >= off) v += A[ii - off];
            Bp[ii] = v;
        }
        __syncthreads();
        int* tmp = A; A = Bp; Bp = tmp;
    }
    // A = inclusive scan of padded counts; Bp = free buffer -> cursors
#pragma unroll
    for (int u = 0; u < 2; ++u) {
        int ii = t + 256 * u;
        int cnt = hc[ii];
        int cp = (cnt + 7) & ~7;
        int excl = A[ii] - cp;
        Bp[ii] = excl;                  // scatter cursor (bucket-local)
        int n = n0 + ii;
        if (n < n_nodes) {
            rowbeg[n] = b * ESCAP + excl;
            degp[n] = cp;
            dinv[n] = rsqrtf((float)cnt + 1.0f);   // true degree + self-loop
        }
    }
    __syncthreads();
    int* es = esrc + (size_t)b * ESCAP;
    i = 4 * t;
    for (; i + 3 < cb; i += 1024) {
        uint4 e4 = *(const uint4*)&eb[i];
#pragma unroll
        for (int u = 0; u < 4; ++u) {
            unsigned e = (&e4.x)[u];
            int r = atomicAdd(&Bp[e >> 17], 1);
            es[r] = (int)(e & 0x1FFFFu);
        }
    }
    for (; i < cb; ++i) {
        unsigned e = eb[i];
        int r = atomicAdd(&Bp[e >> 17], 1);
        es[r] = (int)(e & 0x1FFFFu);
    }
    __syncthreads();
#pragma unroll
    for (int u = 0; u < 2; ++u) {
        int ii = t + 256 * u;
        int end = A[ii];                          // excl + padded count
        for (int p = Bp[ii]; p < end; ++p) es[p] = n_nodes;   // dummy pad
    }
}

// y = fp16((x @ W1) * dinv[n]) via MFMA 16x16x32 f16. Block = 4 waves = 64 rows.
__global__ __launch_bounds__(256, 4) void k_gemm1(
    const float* __restrict__ x, const __half* __restrict__ W1f,
    const float* __restrict__ dinv, __half* __restrict__ y, int n_nodes) {
    __shared__ __half xh[64 * XPAD];
    const int tid = threadIdx.x;
    const int lane = tid & 63;
    const int w = tid >> 6;
    const int row0 = blockIdx.x * 64;

    half8 bf[16];
    const uint4* wf = (const uint4*)W1f;
#pragma unroll
    for (int sc = 0; sc < 16; ++sc) {
        union { uint4 u; half8 h; } tmp;
        tmp.u = wf[sc * 64 + lane];
        bf[sc] = tmp.h;
    }

    for (int i = tid; i < 64 * 32; i += 256) {
        int r = i >> 5, k4 = i & 31;
        int gr = row0 + r;
        if (gr < n_nodes) {
            float4 v = *(const float4*)&x[(size_t)gr * F + 4 * k4];
            __half2 p0 = __floats2half2_rn(v.x, v.y);
            __half2 p1 = __floats2half2_rn(v.z, v.w);
            uint2 pk = make_uint2(*(unsigned*)&p0, *(unsigned*)&p1);
            *(uint2*)&xh[r * XPAD + 4 * k4] = pk;
        }
    }
    __syncthreads();

    const int m16 = lane & 15, quad = lane >> 4;
    floatx4 acc[4];
#pragma unroll
    for (int c = 0; c < 4; ++c) acc[c] = (floatx4){0.f, 0.f, 0.f, 0.f};
#pragma unroll
    for (int s = 0; s < 4; ++s) {
        union { uint4 u; half8 h; } ua;
        ua.u = *(const uint4*)&xh[(16 * w + m16) * XPAD + s * 32 + quad * 8];
#pragma unroll
        for (int c = 0; c < 4; ++c)
            acc[c] = __builtin_amdgcn_mfma_f32_16x16x32_f16(ua.h, bf[s * 4 + c],
                                                            acc[c], 0, 0, 0);
    }
#pragma unroll
    for (int r = 0; r < 4; ++r) {
        int grow = row0 + 16 * w + quad * 4 + r;
        if (grow < n_nodes) {
            float d = dinv[grow];
#pragma unroll
            for (int c = 0; c < 4; ++c)
                y[(size_t)grow * H + c * 16 + m16] = __float2half(acc[c][r] * d);
        }
    }
}

// Fused layer-1 gather + ReLU + W2 projection:
// 8 lanes/node (lane octet c in [0,8) owns features 8c..8c+7), 8 nodes/wave,
// 32 nodes/block. Row reads are uint4 (16B x 8 lanes = full 128B y row).
// 8 edge indices per batch (one scalar esrc load per lane; degp mult of 8).
// Epilogue: h = relu(dinv*agg + b1) in regs; per-lane partials for ALL 10
// outputs vs W2 staged transposed in LDS [10][64] (float4 reads, lane stride
// 32B -> 2-way bank aliasing = free, cross-group broadcast); 3-step xor fold
// within the 8-lane group; lane c==0 stores the packed 24B zs row.
__global__ __launch_bounds__(256) void k_gather1z(
    const uint4* __restrict__ yq4, const int* __restrict__ rowbeg,
    const int* __restrict__ degp, const int* __restrict__ esrc,
    const float* __restrict__ dinv, const float* __restrict__ b1,
    const float* __restrict__ W2, unsigned* __restrict__ zs_u, int n_nodes) {
    __shared__ float w2t[O * H];   // 2.56 KB, transposed: w2t[j*64+k] = W2[k*10+j]
    for (int i = threadIdx.x; i < O * H; i += 256)
        w2t[i] = W2[(i & 63) * O + (i >> 6)];
    __syncthreads();
    const int l = threadIdx.x & 63;
    const int c = l & 7;            // feature octet
    const int gbase = l & ~7;       // first lane of this node's group
    const int n = blockIdx.x * 32 + (threadIdx.x >> 3);
    if (n >= n_nodes) return;       // after the only sync: safe
    const int beg = rowbeg[n];
    const int dp = degp[n];
    const float d = dinv[n];

    float acc[8];
    {   // self-loop: whole group adds its own node's row
        uint4 v = yq4[(size_t)n * 8 + c];
        float2 f0 = __half22float2(*(const __half2*)&v.x);
        float2 f1 = __half22float2(*(const __half2*)&v.y);
        float2 f2 = __half22float2(*(const __half2*)&v.z);
        float2 f3 = __half22float2(*(const __half2*)&v.w);
        acc[0] = f0.x; acc[1] = f0.y; acc[2] = f1.x; acc[3] = f1.y;
        acc[4] = f2.x; acc[5] = f2.y; acc[6] = f3.x; acc[7] = f3.y;
    }
    for (int k0 = 0; k0 < dp; k0 += 8) {
        int idx = esrc[beg + k0 + c];    // 8 edges (beg,dp multiples of 8)
#pragma unroll
        for (int e = 0; e < 8; ++e) {
            int s = __shfl(idx, gbase + e, 64);
            uint4 v = yq4[(size_t)s * 8 + c];
            float2 f0 = __half22float2(*(const __half2*)&v.x);
            float2 f1 = __half22float2(*(const __half2*)&v.y);
            float2 f2 = __half22float2(*(const __half2*)&v.z);
            float2 f3 = __half22float2(*(const __half2*)&v.w);
            acc[0] += f0.x; acc[1] += f0.y; acc[2] += f1.x; acc[3] += f1.y;
            acc[4] += f2.x; acc[5] += f2.y; acc[6] += f3.x; acc[7] += f3.y;
        }
    }
    // h (fp32) for this lane's feature octet
    const float4 ba = ((const float4*)b1)[2 * c];
    const float4 bbv = ((const float4*)b1)[2 * c + 1];
    float h[8];
    h[0] = fmaxf(fmaf(d, acc[0], ba.x), 0.0f);
    h[1] = fmaxf(fmaf(d, acc[1], ba.y), 0.0f);
    h[2] = fmaxf(fmaf(d, acc[2], ba.z), 0.0f);
    h[3] = fmaxf(fmaf(d, acc[3], ba.w), 0.0f);
    h[4] = fmaxf(fmaf(d, acc[4], bbv.x), 0.0f);
    h[5] = fmaxf(fmaf(d, acc[5], bbv.y), 0.0f);
    h[6] = fmaxf(fmaf(d, acc[6], bbv.z), 0.0f);
    h[7] = fmaxf(fmaf(d, acc[7], bbv.w), 0.0f);
    // per-lane partials for all 10 outputs (indices compile-time after unroll)
    float p[O];
#pragma unroll
    for (int j = 0; j < O; ++j) {
        float4 wa = *(const float4*)&w2t[j * 64 + 8 * c];
        float4 wb = *(const float4*)&w2t[j * 64 + 8 * c + 4];
        p[j] = h[0] * wa.x + h[1] * wa.y + h[2] * wa.z + h[3] * wa.w
             + h[4] * wb.x + h[5] * wb.y + h[6] * wb.z + h[7] * wb.w;
    }
#pragma unroll
    for (int m = 1; m <= 4; m <<= 1) {      // fold the 8-lane group
#pragma unroll
        for (int j = 0; j < O; ++j) p[j] += __shfl_xor(p[j], m, 64);
    }
    if (c == 0) {
        __half2 q0 = __floats2half2_rn(p[0] * d, p[1] * d);
        __half2 q1 = __floats2half2_rn(p[2] * d, p[3] * d);
        __half2 q2 = __floats2half2_rn(p[4] * d, p[5] * d);
        __half2 q3 = __floats2half2_rn(p[6] * d, p[7] * d);
        __half2 q4 = __floats2half2_rn(p[8] * d, p[9] * d);
        uint2* zp = (uint2*)&zs_u[(size_t)n * PSU];   // n*24B, 8B-aligned
        zp[0] = make_uint2(*(const unsigned*)&q0, *(const unsigned*)&q1);
        zp[1] = make_uint2(*(const unsigned*)&q2, *(const unsigned*)&q3);
        zp[2] = make_uint2(*(const unsigned*)&q4, 0u);   // zero pad uint
    }
}

// out[n][j] = dinv[n] * (zs[n][j] + sum_k zs[esrc[k]][j]) + b2[j]   (fp32 out)
// 4 lanes/node, uint2 zs reads (lane j owns output pairs {2j,2j+1}); 16
// nodes/wave, 64 nodes/block. Lane 3 re-reads slot 2 — there is NO cross-lane
// fold, its accumulator is never written, so no masking/redirect is needed.
__global__ __launch_bounds__(256) void k_gather2(
    const unsigned* __restrict__ zs_u, const int* __restrict__ rowbeg,
    const int* __restrict__ degp, const int* __restrict__ esrc,
    const float* __restrict__ dinv, const float* __restrict__ b2,
    float* __restrict__ out, int n_nodes) {
    const int l = threadIdx.x & 63;
    const int j = l & 3;
    const int gb = l & ~3;
    const int jj = (j < 3) ? j : 2;         // lane 3: spectator (dup of slot 2)
    const int n = blockIdx.x * 64 + (threadIdx.x >> 2);
    if (n >= n_nodes) return;
    const int beg = rowbeg[n];
    const int dp = degp[n];
    uint2 v0 = *(const uint2*)&zs_u[(size_t)n * PSU + 2 * jj];
    float2 accA = __half22float2(*(const __half2*)&v0.x);
    float2 accB = __half22float2(*(const __half2*)&v0.y);
    for (int k0 = 0; k0 < dp; k0 += 8) {
        int2 idx = *(const int2*)&esrc[beg + k0 + 2 * j];   // 8 edges (8B-aligned)
#pragma unroll
        for (int e = 0; e < 8; ++e) {
            int s = __shfl((e & 1) ? idx.y : idx.x, gb + (e >> 1), 64);
            uint2 v = *(const uint2*)&zs_u[(size_t)s * PSU + 2 * jj];
            float2 fA = __half22float2(*(const __half2*)&v.x);
            float2 fB = __half22float2(*(const __half2*)&v.y);
            accA.x += fA.x; accA.y += fA.y;
            accB.x += fB.x; accB.y += fB.y;
        }
    }
    if (j < 3) {
        const float d = dinv[n];
        float2 bbA = ((const float2*)b2)[2 * j];
        float2 oA = make_float2(fmaf(d, accA.x, bbA.x), fmaf(d, accA.y, bbA.y));
        *(float2*)&out[(size_t)n * O + 4 * j] = oA;       // outputs 4j,4j+1
        if (j < 2) {
            float2 bbB = ((const float2*)b2)[2 * j + 1];
            float2 oB = make_float2(fmaf(d, accB.x, bbB.x), fmaf(d, accB.y, bbB.y));
            *(float2*)&out[(size_t)n * O + 4 * j + 2] = oB;   // outputs 4j+2,4j+3
        }
    }
}

static inline size_t align256(size_t v) { return (v + 255) & ~(size_t)255; }

extern "C" void kernel_launch(void* const* d_in, const int* in_sizes, int n_in,
                              void* d_out, int out_size, void* d_ws, size_t ws_size,
                              hipStream_t stream) {
    const float* x  = (const float*)d_in[0];
    const int*   ei = (const int*)d_in[1];
    const float* W1 = (const float*)d_in[2];
    const float* b1 = (const float*)d_in[3];
    const float* W2 = (const float*)d_in[4];
    const float* b2 = (const float*)d_in[5];
    float* out = (float*)d_out;

    const int N = in_sizes[0] / F;   // 100000
    const int E = in_sizes[1] / 2;   // 1600000
    const int* src = ei;
    const int* dst = ei + E;
    const int NBUK = (N + 511) >> 9;            // 196

    // Workspace (bytes): y[(N+1)*H fp16] | scratch-region[N*H fp16] (front
    // aliased by ebuf 9.63MB, consumed by k_bsort; last 16KB = W1f) | zs[(N+1)
    // *PSU uints] | dinv[N] | rowbeg[N] | degp[N] | bcntg[256]
    // | esrc[NBUK*ESCAP + 64]
    char* base = (char*)d_ws;
    __half* y = (__half*)base;
    size_t ysz = align256((size_t)(N + 1) * H * 2);
    char* hreg = base + ysz;
    unsigned* ebuf = (unsigned*)hreg;                       // 9.63MB <= 12.78MB
    __half* W1f = (__half*)(hreg + (size_t)N * H * 2 - (size_t)F * H * 2);
    size_t hsz = align256((size_t)N * H * 2);
    char* zreg = hreg + hsz;
    unsigned* zs_u = (unsigned*)zreg;
    size_t zsz = align256((size_t)(N + 1) * PSU * 4);
    float* dinv = (float*)(zreg + zsz);
    int* rowbeg = (int*)(dinv + N);
    int* degp = rowbeg + N;
    int* bcntg = degp + N;
    int* esrc = bcntg + 256;

    const int nb_bin = (E + EPB - 1) / EPB;     // 391

    k_init<<<1 + F * H / 256, 256, 0, stream>>>(bcntg, W1, W1f,
                                                (unsigned*)(y + (size_t)N * H),
                                                zs_u + (size_t)N * PSU);
    k_bin<<<nb_bin, 256, 0, stream>>>(src, dst, bcntg, ebuf, E);
    k_bsort<<<NBUK, 256, 0, stream>>>(ebuf, bcntg, rowbeg, degp, dinv, esrc, N);
    k_gemm1<<<(N + 63) / 64, 256, 0, stream>>>(x, W1f, dinv, y, N);
    k_gather1z<<<(N + 31) / 32, 256, 0, stream>>>((const uint4*)y, rowbeg, degp,
                                                  esrc, dinv, b1, W2, zs_u, N);
    k_gather2<<<(N + 63) / 64, 256, 0, stream>>>(zs_u, rowbeg, degp, esrc,
                                                 dinv, b2, out, N);
}